// Round 8
// baseline (1327.638 us; speedup 1.0000x reference)
//
#include <hip/hip_runtime.h>
#include <cstdint>
#include <cstddef>

#define BB 16
#define NN 4096
#define CC 64
#define MM 1024
#define KK 64
#define HH 128
#define NEGV -1.0e30f

#define FTH 256    // fps active threads (4 waves, 1/SIMD)
#define FPT 16     // points per thread (FTH*FPT == NN)
#define NPROD 16   // producer blocks (one per batch)
#define GTOT 256   // 1 block per CU
#define PSTRIDE 32 // progress counter stride in u32 (128B line per batch)

#define KC1 96     // layer-1 K dim padded (67 -> 96)
#define SA 104     // LDS stride of feat planes
#define SH 136     // LDS stride of h1 planes
#define HSTRIDE 41984  // per-half consumer LDS region

typedef __attribute__((ext_vector_type(8))) short bf16x8;
typedef __attribute__((ext_vector_type(4))) float f32x4;
typedef __attribute__((ext_vector_type(2))) float f32x2;

__device__ __forceinline__ unsigned int f2bf(float f) {
  unsigned int u = __float_as_uint(f);
  return (u + 0x7fffu + ((u >> 16) & 1u)) >> 16;
}
__device__ __forceinline__ void split2(float f, unsigned int& h, unsigned int& l) {
  h = f2bf(f);
  float hf = __uint_as_float(h << 16);
  l = f2bf(f - hf);
}

// f32 max across the wave via the proven DPP control sequence; lane 63 ends
// with the wave max (same ctrl/row-mask steps as the verified u64 chain).
template <int CTRL, int RM>
__device__ __forceinline__ float dppmaxf(float v) {
  int s = __builtin_amdgcn_update_dpp(__float_as_int(v), __float_as_int(v),
                                      CTRL, RM, 0xf, false);
  return fmaxf(v, __int_as_float(s));
}

// ---------------------------------------------------------------------------
// Weight prep + progress/claim init (block 0). pn computed inline by consumers.
// ---------------------------------------------------------------------------
__global__ __launch_bounds__(128) void wprep_kernel(
    const float* __restrict__ W1, const float* __restrict__ W2,
    unsigned short* __restrict__ W1Th, unsigned short* __restrict__ W1Tl,
    unsigned short* __restrict__ W2Th, unsigned short* __restrict__ W2Tl,
    unsigned int* __restrict__ progress, unsigned int* __restrict__ claim) {
  const int n = blockIdx.x, t = threadIdx.x;
  if (n == 0) {
    for (int j = t; j < NPROD * PSTRIDE; j += 128) progress[j] = 0u;
    if (t == 0) *claim = 0u;
  }
  if (t < KC1) {
    float v = (t < 67) ? W1[(size_t)t * HH + n] : 0.0f;
    unsigned int h, l; split2(v, h, l);
    W1Th[n * KC1 + t] = (unsigned short)h;
    W1Tl[n * KC1 + t] = (unsigned short)l;
  }
  {
    float v = W2[(size_t)t * HH + n];
    unsigned int h, l; split2(v, h, l);
    W2Th[n * HH + t] = (unsigned short)h;
    W2Tl[n * HH + t] = (unsigned short)l;
  }
}

// ---------------------------------------------------------------------------
// FUSED producer-consumer kernel, R22. Runtime == FPS critical path.
// R21 (-19us) confirmed: serial-chain latency removal pays at modeled value.
// Remaining chain after the barrier had TWO dependent LDS round trips:
// cand read (~130cy) -> compare -> P4[fi] read (~130cy). R22 deletes the
// second one by carrying the winner's COORDINATES through the reduce:
//  (1) (val,idx) tournament unchanged; then a 4-level binary select tree on
//      bj's bits extracts the lane-winner coords (45 cndmask, depth 4) —
//      scheduled INTO the DPP chain's bubbles (independent), ~free.
//  (2) ballot/ctz -> wl; readlane coords from wl (SGPR lane idx — no dynamic
//      register indexing); lane 63 writes ONE 16B slot {valbits, x, y, z}.
//  (3) after the raw barrier: read 4 slots, 2-level component-wise select on
//      valbits (u32 cmp == f32 cmp for non-negative distances; strict >
//      keeps lower wave id == smaller global index). s ready in ONE trip.
// P4 (64KB LDS staging + startup fill) deleted from the producer.
// Tie-break hierarchy unchanged from R21 (left-biased tournament, ctz lane,
// lowest wave) -> selections bit-identical, absmax 0.015625.
// ---------------------------------------------------------------------------
__global__ __launch_bounds__(512, 2) void fused_kernel(
    const float* __restrict__ pos, const float* __restrict__ x,
    float* __restrict__ pos_s_ws, float* __restrict__ pos_s_out,
    const unsigned short* __restrict__ W1Th, const unsigned short* __restrict__ W1Tl,
    const unsigned short* __restrict__ W2Th, const unsigned short* __restrict__ W2Tl,
    const float* __restrict__ b1, const float* __restrict__ b2,
    float* __restrict__ out,
    unsigned int* __restrict__ progress, unsigned int* __restrict__ claim) {
#pragma clang fp contract(off)
  __shared__ __attribute__((aligned(16))) unsigned char LBUF[83968];
  const int t = threadIdx.x;
  const int lane = t & 63;

  if (blockIdx.x < NPROD) {
    // =================== PRODUCER: FPS for batch b ===================
    if (t >= FTH) return;            // waves 4..7 exit; barrier counts live waves
    __builtin_amdgcn_s_setprio(3);
    const int wv = t >> 6;           // 0..3
    const int b = blockIdx.x;
    float* SXa = (float*)(LBUF);                         // 4096 B
    float* SYa = (float*)(LBUF + 4096);                  // 4096 B
    float* SZa = (float*)(LBUF + 8192);                  // 4096 B
    unsigned int* cand = (unsigned int*)(LBUF + 12288);  // [2][4] x uint4
    const float* pb = pos + (size_t)b * NN * 3;

    // chunk-register fill: this thread owns points t*16 .. t*16+15
    // (lane order == global index order -> ballot tie-break is exact)
    f32x2 px[8], py[8], pz[8], dd[8];
    {
      const float4* pc4 = (const float4*)(pb + (size_t)t * 48);
      float4 f4[12];
#pragma unroll
      for (int ii = 0; ii < 12; ++ii) f4[ii] = pc4[ii];
      const float* ff = (const float*)f4;
#pragma unroll
      for (int l = 0; l < 16; ++l) {
        px[l >> 1][l & 1] = ff[l * 3 + 0];
        py[l >> 1][l & 1] = ff[l * 3 + 1];
        pz[l >> 1][l & 1] = ff[l * 3 + 2];
        dd[l >> 1][l & 1] = 3.4028234663852886e38f;
      }
    }
    // seed = point 0 (uniform scalar loads, L2 broadcast)
    float sx = pb[0], sy = pb[1], sz = pb[2];
    if (t == 0) { SXa[0] = sx; SYa[0] = sy; SZa[0] = sz; }

    for (int m = 1; m < MM; ++m) {
      f32x2 s2x = {sx, sx}, s2y = {sy, sy}, s2z = {sz, sz};
      // distance update + tournament L1 fused (left-biased: first-max kept)
      float tv[8]; int ti[8];
#pragma unroll
      for (int k = 0; k < 8; ++k) {
        f32x2 dx = px[k] - s2x, dy = py[k] - s2y, dz = pz[k] - s2z;
        f32x2 d2 = (dx * dx + dy * dy) + dz * dz;   // v_pk_*, no FMA (pragma)
        float n0 = fminf(dd[k][0], d2[0]);
        float n1 = fminf(dd[k][1], d2[1]);
        dd[k][0] = n0;
        dd[k][1] = n1;
        bool c = n1 > n0;
        tv[k] = c ? n1 : n0;
        ti[k] = c ? (2 * k + 1) : (2 * k);
      }
      // tournament L2..L4
      float uv[4]; int ui[4];
#pragma unroll
      for (int k = 0; k < 4; ++k) {
        bool c = tv[2 * k + 1] > tv[2 * k];
        uv[k] = c ? tv[2 * k + 1] : tv[2 * k];
        ui[k] = c ? ti[2 * k + 1] : ti[2 * k];
      }
      float wv2[2]; int wi2[2];
#pragma unroll
      for (int k = 0; k < 2; ++k) {
        bool c = uv[2 * k + 1] > uv[2 * k];
        wv2[k] = c ? uv[2 * k + 1] : uv[2 * k];
        wi2[k] = c ? ui[2 * k + 1] : ui[2 * k];
      }
      bool cf = wv2[1] > wv2[0];
      float bv = cf ? wv2[1] : wv2[0];
      int bj = cf ? wi2[1] : wi2[0];   // winning local index 0..15

      // wave reduce on value (DPP chain) ...
      float mx = bv;
      mx = dppmaxf<0x111, 0xf>(mx);
      mx = dppmaxf<0x112, 0xf>(mx);
      mx = dppmaxf<0x114, 0xf>(mx);
      mx = dppmaxf<0x118, 0xf>(mx);
      mx = dppmaxf<0x142, 0xa>(mx);
      mx = dppmaxf<0x143, 0xc>(mx);
      // ... concurrent: binary select tree extracts this lane's winner coords
      // (independent of DPP chain -> fills its latency bubbles)
      bool s0 = (bj & 1) != 0;
      bool s1 = (bj & 2) != 0;
      bool s2b = (bj & 4) != 0;
      bool s3 = (bj & 8) != 0;
      float ax[8], ay[8], az[8];
#pragma unroll
      for (int k = 0; k < 8; ++k) {
        ax[k] = s0 ? px[k][1] : px[k][0];
        ay[k] = s0 ? py[k][1] : py[k][0];
        az[k] = s0 ? pz[k][1] : pz[k][0];
      }
      float bx4[4], by4[4], bz4[4];
#pragma unroll
      for (int k = 0; k < 4; ++k) {
        bx4[k] = s1 ? ax[2 * k + 1] : ax[2 * k];
        by4[k] = s1 ? ay[2 * k + 1] : ay[2 * k];
        bz4[k] = s1 ? az[2 * k + 1] : az[2 * k];
      }
      float cx2[2], cy2[2], cz2[2];
#pragma unroll
      for (int k = 0; k < 2; ++k) {
        cx2[k] = s2b ? bx4[2 * k + 1] : bx4[2 * k];
        cy2[k] = s2b ? by4[2 * k + 1] : by4[2 * k];
        cz2[k] = s2b ? bz4[2 * k + 1] : bz4[2 * k];
      }
      float bx = s3 ? cx2[1] : cx2[0];
      float by = s3 ? cy2[1] : cy2[0];
      float bz = s3 ? cz2[1] : cz2[0];

      float wavemax = __int_as_float(
          __builtin_amdgcn_readlane(__float_as_int(mx), 63));
      unsigned long long ball = __ballot(bv == wavemax);
      int wl = (int)__builtin_ctzll(ball);       // lowest lane == smallest idx
      float wx = __int_as_float(
          __builtin_amdgcn_readlane(__float_as_int(bx), wl));
      float wy = __int_as_float(
          __builtin_amdgcn_readlane(__float_as_int(by), wl));
      float wz = __int_as_float(
          __builtin_amdgcn_readlane(__float_as_int(bz), wl));

      const int p16 = (m & 1) * 16;              // parity slot base (u32 units)
      if (lane == 63) {
        unsigned int* slot = cand + p16 + wv * 4;
        *(uint4*)slot = make_uint4(__float_as_uint(wavemax),
                                   __float_as_uint(wx),
                                   __float_as_uint(wy),
                                   __float_as_uint(wz));
      }
      // raw barrier: drain LDS (cand write) only — no vmcnt drain here.
      asm volatile("s_waitcnt lgkmcnt(0)" ::: "memory");
      __builtin_amdgcn_s_barrier();
      asm volatile("" ::: "memory");

      uint4 c0 = *(const uint4*)(cand + p16 + 0);
      uint4 c1 = *(const uint4*)(cand + p16 + 4);
      uint4 c2 = *(const uint4*)(cand + p16 + 8);
      uint4 c3 = *(const uint4*)(cand + p16 + 12);
      // pairwise select on valbits; strict > keeps the LOWER wave id on ties
      // (u32 compare == f32 compare for non-negative distances)
      bool q1 = c1.x > c0.x;
      uint4 e; e.x = q1 ? c1.x : c0.x; e.y = q1 ? c1.y : c0.y;
      e.z = q1 ? c1.z : c0.z; e.w = q1 ? c1.w : c0.w;
      bool q2 = c3.x > c2.x;
      uint4 f; f.x = q2 ? c3.x : c2.x; f.y = q2 ? c3.y : c2.y;
      f.z = q2 ? c3.z : c2.z; f.w = q2 ? c3.w : c2.w;
      bool q3 = f.x > e.x;
      sx = __uint_as_float(q3 ? f.y : e.y);
      sy = __uint_as_float(q3 ? f.z : e.z);
      sz = __uint_as_float(q3 ? f.w : e.w);

      if (t == 0) { SXa[m] = sx; SYa[m] = sy; SZa[m] = sz; }
      if ((m & 15) == 15) {
        // parallel flush: lanes 0..15 of wave0 each publish one center.
        // SXa[idx] written by lane0 of the SAME wave (in-order DS).
        if (t < 16) {
          int idx = (m - 15) + t;
          float fx = SXa[idx], fy = SYa[idx], fz = SZa[idx];
          size_t o = ((size_t)b * MM + idx) * 3;
          __hip_atomic_store(&pos_s_ws[o + 0], fx, __ATOMIC_RELAXED, __HIP_MEMORY_SCOPE_AGENT);
          __hip_atomic_store(&pos_s_ws[o + 1], fy, __ATOMIC_RELAXED, __HIP_MEMORY_SCOPE_AGENT);
          __hip_atomic_store(&pos_s_ws[o + 2], fz, __ATOMIC_RELAXED, __HIP_MEMORY_SCOPE_AGENT);
        }
      } else if ((m & 15) == 0 && t == 0) {
        // hand-rolled release: wave0's flush stores (issued one iter ago)
        // complete at the coherence point before progress publishes.
        asm volatile("s_waitcnt vmcnt(0)" ::: "memory");
        __hip_atomic_store(&progress[b * PSTRIDE], (unsigned int)m,
                           __ATOMIC_RELAXED, __HIP_MEMORY_SCOPE_AGENT);
      }
    }
    __syncthreads();   // full barrier: SXa final values visible to all threads
    if (t == 0) {
      // final publish: last flush (m=1023) covered centers 1008..1023.
      asm volatile("s_waitcnt vmcnt(0)" ::: "memory");
      __hip_atomic_store(&progress[b * PSTRIDE], (unsigned int)MM,
                         __ATOMIC_RELAXED, __HIP_MEMORY_SCOPE_AGENT);
    }
    for (int i = t; i < MM; i += FTH) {
      size_t o = ((size_t)b * MM + i) * 3;
      pos_s_out[o + 0] = SXa[i];
      pos_s_out[o + 1] = SYa[i];
      pos_s_out[o + 2] = SZa[i];
    }
    return;
  }

  // ============ CONSUMER: two 4-wave pipelines (halves h=0,1) ============
  const int h = t >> 8;            // half id
  const int th = t & 255;          // half-local thread id
  const int wvh = (t >> 6) & 3;    // half-local wave id
  unsigned char* HB = LBUF + h * HSTRIDE;
  unsigned short* Ah = (unsigned short*)HB;
  unsigned short* Al = (unsigned short*)(HB + 64 * SA * 2);
  unsigned short* Hh = (unsigned short*)HB;
  unsigned short* Hl = (unsigned short*)(HB + 64 * SH * 2);
  int* nbr_s = (int*)(HB + 34816);
  unsigned long long* masksL = (unsigned long long*)(HB + 35072);
  int* prefixL = (int*)(HB + 35584);
  float* ctr = (float*)(HB + 35840);
  int* cntS = (int*)(HB + 35856);
  volatile int* cidShare = (int*)(LBUF + 83960);   // block-wide
  const int r = lane & 15, q = lane >> 4;
  const int wbase = wvh * 32;

  while (true) {
    if (t == 0) {
      unsigned int i = __hip_atomic_fetch_add(claim, 2u, __ATOMIC_RELAXED,
                                              __HIP_MEMORY_SCOPE_AGENT);
      *cidShare = (int)i;
    }
    __syncthreads();
    int i0 = *cidShare;
    if (i0 >= BB * MM) break;                      // uniform exit
    const int i = i0 + h;
    const bool active = (i < BB * MM);
    const int cid = active ? (((i & 15) << 10) | (i >> 4)) : 0;
    const int b = cid >> 10;
    const int m = cid & 1023;

    if (active && th < 64) {   // half's wave 0 polls production progress
      while ((int)__hip_atomic_load(&progress[b * PSTRIDE], __ATOMIC_RELAXED,
                                    __HIP_MEMORY_SCOPE_AGENT) <= m)
        __builtin_amdgcn_s_sleep(64);
    }
    if (active && th < 3)
      ctr[th] = __hip_atomic_load(&pos_s_ws[(size_t)cid * 3 + th],
                                  __ATOMIC_RELAXED, __HIP_MEMORY_SCOPE_AGENT);
    __syncthreads();

    // ---- ballq: 4-wave mask pass + prefix + compaction (per half) ----
    const float sx = ctr[0], sy = ctr[1], sz = ctr[2];
    const float sn = (sx * sx + sy * sy) + sz * sz;
    const float* pb = pos + (size_t)b * NN * 3;
    if (active) {
#pragma unroll
      for (int cc = 0; cc < 16; ++cc) {
        int c = (wvh << 4) + cc;
        int n = (c << 6) + lane;
        float xx = pb[n * 3 + 0], yy = pb[n * 3 + 1], zz = pb[n * 3 + 2];
        float pnn = (xx * xx + yy * yy) + zz * zz;  // == old pn[n] bitwise
        float dot = __builtin_fmaf(sz, zz, __builtin_fmaf(sy, yy, sx * xx));
        float d2 = (sn + pnn) - 2.0f * dot;
        bool pred = d2 <= 0.04f;
        unsigned long long mask = __ballot(pred);
        if (lane == 0) masksL[c] = mask;
      }
    }
    __syncthreads();
    if (active && th < 64) {
      int pc = (int)__popcll(masksL[lane]);
      int incl = pc;
#pragma unroll
      for (int off = 1; off < 64; off <<= 1) {
        int o2 = __shfl_up(incl, off, 64);
        if (lane >= off) incl += o2;
      }
      prefixL[lane] = incl - pc;
      if (lane == 63) *cntS = incl < KK ? incl : KK;
    }
    __syncthreads();
    const int cnt = *cntS;
    if (active) {
#pragma unroll
      for (int cc = 0; cc < 16; ++cc) {
        int c = (wvh << 4) + cc;
        unsigned long long mk = masksL[c];
        bool pred = (mk >> lane) & 1ull;
        int slot = prefixL[c] + (int)__popcll(mk & ((1ull << lane) - 1ull));
        if (pred && slot < KK) nbr_s[slot] = (c << 6) + lane;
      }
    }
    __syncthreads();

    // ---- gather + hi/lo split into LDS feat planes ----
    if (active) {
      const int kn = th >> 2, p = th & 3;
      float vals[16];
      float d0 = 0.0f, d1 = 0.0f, d2v = 0.0f;
      if (kn < cnt) {
        int n = nbr_s[kn];
        const float* xp = x + ((size_t)b * NN + n) * CC + p * 16;
#pragma unroll
        for (int ii = 0; ii < 4; ++ii) {
          float4 v = ((const float4*)xp)[ii];
          vals[ii * 4 + 0] = v.x; vals[ii * 4 + 1] = v.y;
          vals[ii * 4 + 2] = v.z; vals[ii * 4 + 3] = v.w;
        }
        if (p == 0) {
          const float* pp = pos + ((size_t)b * NN + n) * 3;
          d0 = pp[0] - sx; d1 = pp[1] - sy; d2v = pp[2] - sz;
        }
      } else {
#pragma unroll
        for (int ii = 0; ii < 16; ++ii) vals[ii] = 0.0f;
      }
#pragma unroll
      for (int j = 0; j < 16; j += 2) {
        unsigned int h0, l0, h1, l1;
        split2(vals[j], h0, l0);
        split2(vals[j + 1], h1, l1);
        int c = p * 16 + j;
        *(unsigned int*)&Ah[kn * SA + c] = h0 | (h1 << 16);
        *(unsigned int*)&Al[kn * SA + c] = l0 | (l1 << 16);
      }
      if (p == 0) {
        unsigned int h0, l0, h1, l1, h2, l2;
        split2(d0, h0, l0); split2(d1, h1, l1); split2(d2v, h2, l2);
        *(unsigned int*)&Ah[kn * SA + 64] = h0 | (h1 << 16);
        *(unsigned int*)&Al[kn * SA + 64] = l0 | (l1 << 16);
        *(unsigned int*)&Ah[kn * SA + 66] = h2;
        *(unsigned int*)&Al[kn * SA + 66] = l2;
      } else if (p == 1) {
#pragma unroll
        for (int c = 68; c < 80; c += 2) {
          *(unsigned int*)&Ah[kn * SA + c] = 0u;
          *(unsigned int*)&Al[kn * SA + c] = 0u;
        }
      } else if (p == 2) {
#pragma unroll
        for (int c = 80; c < 96; c += 2) {
          *(unsigned int*)&Ah[kn * SA + c] = 0u;
          *(unsigned int*)&Al[kn * SA + c] = 0u;
        }
      }
    }
    __syncthreads();

    f32x4 acc[4][2];
#pragma unroll
    for (int mt = 0; mt < 4; ++mt)
#pragma unroll
      for (int nt = 0; nt < 2; ++nt) acc[mt][nt] = (f32x4)0.0f;

    // ---- layer 1 ----
    if (active) {
#pragma unroll
      for (int kc = 0; kc < 3; ++kc) {
        bf16x8 bh[2], bl[2];
#pragma unroll
        for (int nt = 0; nt < 2; ++nt) {
          int o = (wbase + nt * 16 + r) * KC1 + kc * 32 + q * 8;
          bh[nt] = *(const bf16x8*)(W1Th + o);
          bl[nt] = *(const bf16x8*)(W1Tl + o);
        }
#pragma unroll
        for (int mt = 0; mt < 4; ++mt) {
          int o = (mt * 16 + r) * SA + kc * 32 + q * 8;
          bf16x8 ah = *(const bf16x8*)&Ah[o];
          bf16x8 al = *(const bf16x8*)&Al[o];
#pragma unroll
          for (int nt = 0; nt < 2; ++nt) {
            acc[mt][nt] = __builtin_amdgcn_mfma_f32_16x16x32_bf16(ah, bh[nt], acc[mt][nt], 0, 0, 0);
            acc[mt][nt] = __builtin_amdgcn_mfma_f32_16x16x32_bf16(al, bh[nt], acc[mt][nt], 0, 0, 0);
            acc[mt][nt] = __builtin_amdgcn_mfma_f32_16x16x32_bf16(ah, bl[nt], acc[mt][nt], 0, 0, 0);
          }
        }
      }
    }
    __syncthreads();   // alias guard: A-plane reads done before H overwrite

    if (active) {
      float b1v[2] = { b1[wbase + r], b1[wbase + 16 + r] };
#pragma unroll
      for (int mt = 0; mt < 4; ++mt)
#pragma unroll
        for (int nt = 0; nt < 2; ++nt)
#pragma unroll
          for (int ii = 0; ii < 4; ++ii) {
            int mm = mt * 16 + q * 4 + ii;
            int n = wbase + nt * 16 + r;
            float v = fmaxf(acc[mt][nt][ii] + b1v[nt], 0.0f);
            unsigned int hh2, ll2; split2(v, hh2, ll2);
            Hh[mm * SH + n] = (unsigned short)hh2;
            Hl[mm * SH + n] = (unsigned short)ll2;
          }
    }
    __syncthreads();

    // ---- layer 2 + masked max ----
#pragma unroll
    for (int mt = 0; mt < 4; ++mt)
#pragma unroll
      for (int nt = 0; nt < 2; ++nt) acc[mt][nt] = (f32x4)0.0f;
    if (active) {
#pragma unroll
      for (int kc = 0; kc < 4; ++kc) {
        bf16x8 bh[2], bl[2];
#pragma unroll
        for (int nt = 0; nt < 2; ++nt) {
          int o = (wbase + nt * 16 + r) * HH + kc * 32 + q * 8;
          bh[nt] = *(const bf16x8*)(W2Th + o);
          bl[nt] = *(const bf16x8*)(W2Tl + o);
        }
#pragma unroll
        for (int mt = 0; mt < 4; ++mt) {
          int o = (mt * 16 + r) * SH + kc * 32 + q * 8;
          bf16x8 ah = *(const bf16x8*)&Hh[o];
          bf16x8 al = *(const bf16x8*)&Hl[o];
#pragma unroll
          for (int nt = 0; nt < 2; ++nt) {
            acc[mt][nt] = __builtin_amdgcn_mfma_f32_16x16x32_bf16(ah, bh[nt], acc[mt][nt], 0, 0, 0);
            acc[mt][nt] = __builtin_amdgcn_mfma_f32_16x16x32_bf16(al, bh[nt], acc[mt][nt], 0, 0, 0);
            acc[mt][nt] = __builtin_amdgcn_mfma_f32_16x16x32_bf16(ah, bl[nt], acc[mt][nt], 0, 0, 0);
          }
        }
      }
      float b2v[2] = { b2[wbase + r], b2[wbase + 16 + r] };
#pragma unroll
      for (int nt = 0; nt < 2; ++nt) {
        float vmax = NEGV;
#pragma unroll
        for (int mt = 0; mt < 4; ++mt)
#pragma unroll
          for (int ii = 0; ii < 4; ++ii) {
            int mm = mt * 16 + q * 4 + ii;
            float v = fmaxf(acc[mt][nt][ii] + b2v[nt], 0.0f);
            if (mm < cnt) vmax = fmaxf(vmax, v);
          }
        vmax = fmaxf(vmax, __shfl_xor(vmax, 16, 64));
        vmax = fmaxf(vmax, __shfl_xor(vmax, 32, 64));
        if (q == 0)
          out[(size_t)cid * HH + wbase + nt * 16 + r] = (cnt > 0) ? vmax : 0.0f;
      }
    }
    __syncthreads();   // LDS reuse guard before next center
  }
}

// ---------------------------------------------------------------------------
extern "C" void kernel_launch(void* const* d_in, const int* in_sizes, int n_in,
                              void* d_out, int out_size, void* d_ws, size_t ws_size,
                              hipStream_t stream) {
  const float* x   = (const float*)d_in[0];
  const float* pos = (const float*)d_in[1];
  const float* W1  = (const float*)d_in[2];
  const float* b1  = (const float*)d_in[3];
  const float* W2  = (const float*)d_in[4];
  const float* b2  = (const float*)d_in[5];
  float* out = (float*)d_out;
  float* pos_s_out = out + (size_t)BB * MM * HH;

  char* ws = (char*)d_ws;
  float* pos_s_ws = (float*)(ws);                          // 196608 B
  unsigned short* W1Th = (unsigned short*)(ws + 458752);   // 24576 B
  unsigned short* W1Tl = (unsigned short*)(ws + 483328);   // 24576 B
  unsigned short* W2Th = (unsigned short*)(ws + 507904);   // 32768 B
  unsigned short* W2Tl = (unsigned short*)(ws + 540672);   // 32768 B
  unsigned int* progress = (unsigned int*)(ws + 573440);   // 16*128 B
  unsigned int* claim    = (unsigned int*)(ws + 575488);   // 4 B

  wprep_kernel<<<HH, 128, 0, stream>>>(W1, W2, W1Th, W1Tl, W2Th, W2Tl,
                                       progress, claim);
  fused_kernel<<<GTOT, 512, 0, stream>>>(pos, x, pos_s_ws, pos_s_out,
                                         W1Th, W1Tl, W2Th, W2Tl, b1, b2, out,
                                         progress, claim);
}

// Round 9
// 1068.083 us; speedup vs baseline: 1.2430x; 1.2430x over previous
//
#include <hip/hip_runtime.h>
#include <cstdint>
#include <cstddef>

#define BB 16
#define NN 4096
#define CC 64
#define MM 1024
#define KK 64
#define HH 128
#define NEGV -1.0e30f

#define FTH 256    // fps active threads (4 waves, 1/SIMD)
#define FPT 16     // points per thread (FTH*FPT == NN)
#define NPROD 16   // producer blocks (one per batch)
#define GTOT 256   // 1 block per CU
#define PSTRIDE 32 // progress counter stride in u32 (128B line per batch)

#define KC1 96     // layer-1 K dim padded (67 -> 96)
#define SA 104     // LDS stride of feat planes
#define SH 136     // LDS stride of h1 planes
#define HSTRIDE 41984  // per-half consumer LDS region

typedef __attribute__((ext_vector_type(8))) short bf16x8;
typedef __attribute__((ext_vector_type(4))) float f32x4;
typedef __attribute__((ext_vector_type(2))) float f32x2;

__device__ __forceinline__ unsigned int f2bf(float f) {
  unsigned int u = __float_as_uint(f);
  return (u + 0x7fffu + ((u >> 16) & 1u)) >> 16;
}
__device__ __forceinline__ void split2(float f, unsigned int& h, unsigned int& l) {
  h = f2bf(f);
  float hf = __uint_as_float(h << 16);
  l = f2bf(f - hf);
}

// f32 max across the wave via the proven DPP control sequence; lane 63 ends
// with the wave max (same ctrl/row-mask steps as the verified u64 chain).
template <int CTRL, int RM>
__device__ __forceinline__ float dppmaxf(float v) {
  int s = __builtin_amdgcn_update_dpp(__float_as_int(v), __float_as_int(v),
                                      CTRL, RM, 0xf, false);
  return fmaxf(v, __int_as_float(s));
}

// ---------------------------------------------------------------------------
// Weight prep + progress/claim init (block 0). pn computed inline by consumers.
// ---------------------------------------------------------------------------
__global__ __launch_bounds__(128) void wprep_kernel(
    const float* __restrict__ W1, const float* __restrict__ W2,
    unsigned short* __restrict__ W1Th, unsigned short* __restrict__ W1Tl,
    unsigned short* __restrict__ W2Th, unsigned short* __restrict__ W2Tl,
    unsigned int* __restrict__ progress, unsigned int* __restrict__ claim) {
  const int n = blockIdx.x, t = threadIdx.x;
  if (n == 0) {
    for (int j = t; j < NPROD * PSTRIDE; j += 128) progress[j] = 0u;
    if (t == 0) *claim = 0u;
  }
  if (t < KC1) {
    float v = (t < 67) ? W1[(size_t)t * HH + n] : 0.0f;
    unsigned int h, l; split2(v, h, l);
    W1Th[n * KC1 + t] = (unsigned short)h;
    W1Tl[n * KC1 + t] = (unsigned short)l;
  }
  {
    float v = W2[(size_t)t * HH + n];
    unsigned int h, l; split2(v, h, l);
    W2Th[n * HH + t] = (unsigned short)h;
    W2Tl[n * HH + t] = (unsigned short)l;
  }
}

// ---------------------------------------------------------------------------
// FUSED producer-consumer kernel, R23. Runtime == FPS critical path.
// R22 post-mortem (715->1285): LDS_Block_Size 83968->157696 (+144B/thread
// exactly = ax/ay/az[8] 96B + bx4/by4/bz4[4] 48B) and bank conflicts 2x:
// AMDGPU PromoteAlloca lowered the coord select-tree ARRAYS to LDS -> 45
// LDS ops/iter at conflict-heavy stride. The coord-carry idea itself passed
// (absmax unchanged). R23 = R22 with the select tree FULLY SCALARIZED
// (named scalars only — nothing for PromoteAlloca to grab). Verification:
// LDS_Block_Size must read 83968 and conflicts ~1.47e7 again.
// Chain (unchanged from R22 intent): tournament (val,idx) -> DPP value max
// (bubbles filled by the scalar select tree) -> ballot/ctz -> readlane
// coords -> lane63 writes ONE {valbits,x,y,z} slot -> raw barrier -> 4-slot
// component select (u32 cmp == f32 cmp for non-neg distances; strict >
// keeps lower wave id). ONE LDS round trip/iter; P4 staging deleted.
// Tie-break hierarchy == R21 -> selections bit-identical, absmax 0.015625.
// ---------------------------------------------------------------------------
__global__ __launch_bounds__(512, 2) void fused_kernel(
    const float* __restrict__ pos, const float* __restrict__ x,
    float* __restrict__ pos_s_ws, float* __restrict__ pos_s_out,
    const unsigned short* __restrict__ W1Th, const unsigned short* __restrict__ W1Tl,
    const unsigned short* __restrict__ W2Th, const unsigned short* __restrict__ W2Tl,
    const float* __restrict__ b1, const float* __restrict__ b2,
    float* __restrict__ out,
    unsigned int* __restrict__ progress, unsigned int* __restrict__ claim) {
#pragma clang fp contract(off)
  __shared__ __attribute__((aligned(16))) unsigned char LBUF[83968];
  const int t = threadIdx.x;
  const int lane = t & 63;

  if (blockIdx.x < NPROD) {
    // =================== PRODUCER: FPS for batch b ===================
    if (t >= FTH) return;            // waves 4..7 exit; barrier counts live waves
    __builtin_amdgcn_s_setprio(3);
    const int wv = t >> 6;           // 0..3
    const int b = blockIdx.x;
    float* SXa = (float*)(LBUF);                         // 4096 B
    float* SYa = (float*)(LBUF + 4096);                  // 4096 B
    float* SZa = (float*)(LBUF + 8192);                  // 4096 B
    unsigned int* cand = (unsigned int*)(LBUF + 12288);  // [2][4] x uint4
    const float* pb = pos + (size_t)b * NN * 3;

    // chunk-register fill: this thread owns points t*16 .. t*16+15
    // (lane order == global index order -> ballot tie-break is exact)
    f32x2 px[8], py[8], pz[8], dd[8];
    {
      const float4* pc4 = (const float4*)(pb + (size_t)t * 48);
      float4 f4[12];
#pragma unroll
      for (int ii = 0; ii < 12; ++ii) f4[ii] = pc4[ii];
      const float* ff = (const float*)f4;
#pragma unroll
      for (int l = 0; l < 16; ++l) {
        px[l >> 1][l & 1] = ff[l * 3 + 0];
        py[l >> 1][l & 1] = ff[l * 3 + 1];
        pz[l >> 1][l & 1] = ff[l * 3 + 2];
        dd[l >> 1][l & 1] = 3.4028234663852886e38f;
      }
    }
    // seed = point 0 (uniform scalar loads, L2 broadcast)
    float sx = pb[0], sy = pb[1], sz = pb[2];
    if (t == 0) { SXa[0] = sx; SYa[0] = sy; SZa[0] = sz; }

    for (int m = 1; m < MM; ++m) {
      f32x2 s2x = {sx, sx}, s2y = {sy, sy}, s2z = {sz, sz};
      // distance update + tournament L1 fused (left-biased: first-max kept)
      float tv[8]; int ti[8];
#pragma unroll
      for (int k = 0; k < 8; ++k) {
        f32x2 dx = px[k] - s2x, dy = py[k] - s2y, dz = pz[k] - s2z;
        f32x2 d2 = (dx * dx + dy * dy) + dz * dz;   // v_pk_*, no FMA (pragma)
        float n0 = fminf(dd[k][0], d2[0]);
        float n1 = fminf(dd[k][1], d2[1]);
        dd[k][0] = n0;
        dd[k][1] = n1;
        bool c = n1 > n0;
        tv[k] = c ? n1 : n0;
        ti[k] = c ? (2 * k + 1) : (2 * k);
      }
      // tournament L2..L4
      float uv[4]; int ui[4];
#pragma unroll
      for (int k = 0; k < 4; ++k) {
        bool c = tv[2 * k + 1] > tv[2 * k];
        uv[k] = c ? tv[2 * k + 1] : tv[2 * k];
        ui[k] = c ? ti[2 * k + 1] : ti[2 * k];
      }
      float wv2[2]; int wi2[2];
#pragma unroll
      for (int k = 0; k < 2; ++k) {
        bool c = uv[2 * k + 1] > uv[2 * k];
        wv2[k] = c ? uv[2 * k + 1] : uv[2 * k];
        wi2[k] = c ? ui[2 * k + 1] : ui[2 * k];
      }
      bool cf = wv2[1] > wv2[0];
      float bv = cf ? wv2[1] : wv2[0];
      int bj = cf ? wi2[1] : wi2[0];   // winning local index 0..15

      // wave reduce on value (DPP chain) ...
      float mx = bv;
      mx = dppmaxf<0x111, 0xf>(mx);
      mx = dppmaxf<0x112, 0xf>(mx);
      mx = dppmaxf<0x114, 0xf>(mx);
      mx = dppmaxf<0x118, 0xf>(mx);
      mx = dppmaxf<0x142, 0xa>(mx);
      mx = dppmaxf<0x143, 0xc>(mx);
      // ... concurrent: FULLY SCALARIZED binary select tree (R23: named
      // scalars only — no arrays, nothing for PromoteAlloca to lower to LDS)
      const bool s0 = (bj & 1) != 0;
      const bool s1 = (bj & 2) != 0;
      const bool s2b = (bj & 4) != 0;
      const bool s3 = (bj & 8) != 0;
      float a0x = s0 ? px[0][1] : px[0][0];
      float a1x = s0 ? px[1][1] : px[1][0];
      float a2x = s0 ? px[2][1] : px[2][0];
      float a3x = s0 ? px[3][1] : px[3][0];
      float a4x = s0 ? px[4][1] : px[4][0];
      float a5x = s0 ? px[5][1] : px[5][0];
      float a6x = s0 ? px[6][1] : px[6][0];
      float a7x = s0 ? px[7][1] : px[7][0];
      float a0y = s0 ? py[0][1] : py[0][0];
      float a1y = s0 ? py[1][1] : py[1][0];
      float a2y = s0 ? py[2][1] : py[2][0];
      float a3y = s0 ? py[3][1] : py[3][0];
      float a4y = s0 ? py[4][1] : py[4][0];
      float a5y = s0 ? py[5][1] : py[5][0];
      float a6y = s0 ? py[6][1] : py[6][0];
      float a7y = s0 ? py[7][1] : py[7][0];
      float a0z = s0 ? pz[0][1] : pz[0][0];
      float a1z = s0 ? pz[1][1] : pz[1][0];
      float a2z = s0 ? pz[2][1] : pz[2][0];
      float a3z = s0 ? pz[3][1] : pz[3][0];
      float a4z = s0 ? pz[4][1] : pz[4][0];
      float a5z = s0 ? pz[5][1] : pz[5][0];
      float a6z = s0 ? pz[6][1] : pz[6][0];
      float a7z = s0 ? pz[7][1] : pz[7][0];
      float b0x = s1 ? a1x : a0x;
      float b1x = s1 ? a3x : a2x;
      float b2x = s1 ? a5x : a4x;
      float b3x = s1 ? a7x : a6x;
      float b0y = s1 ? a1y : a0y;
      float b1y = s1 ? a3y : a2y;
      float b2y = s1 ? a5y : a4y;
      float b3y = s1 ? a7y : a6y;
      float b0z = s1 ? a1z : a0z;
      float b1z = s1 ? a3z : a2z;
      float b2z = s1 ? a5z : a4z;
      float b3z = s1 ? a7z : a6z;
      float c0x = s2b ? b1x : b0x;
      float c1x = s2b ? b3x : b2x;
      float c0y = s2b ? b1y : b0y;
      float c1y = s2b ? b3y : b2y;
      float c0z = s2b ? b1z : b0z;
      float c1z = s2b ? b3z : b2z;
      float bx = s3 ? c1x : c0x;
      float by = s3 ? c1y : c0y;
      float bz = s3 ? c1z : c0z;

      float wavemax = __int_as_float(
          __builtin_amdgcn_readlane(__float_as_int(mx), 63));
      unsigned long long ball = __ballot(bv == wavemax);
      int wl = (int)__builtin_ctzll(ball);       // lowest lane == smallest idx
      float wx = __int_as_float(
          __builtin_amdgcn_readlane(__float_as_int(bx), wl));
      float wy = __int_as_float(
          __builtin_amdgcn_readlane(__float_as_int(by), wl));
      float wz = __int_as_float(
          __builtin_amdgcn_readlane(__float_as_int(bz), wl));

      const int p16 = (m & 1) * 16;              // parity slot base (u32 units)
      if (lane == 63) {
        unsigned int* slot = cand + p16 + wv * 4;
        *(uint4*)slot = make_uint4(__float_as_uint(wavemax),
                                   __float_as_uint(wx),
                                   __float_as_uint(wy),
                                   __float_as_uint(wz));
      }
      // raw barrier: drain LDS (cand write) only — no vmcnt drain here.
      asm volatile("s_waitcnt lgkmcnt(0)" ::: "memory");
      __builtin_amdgcn_s_barrier();
      asm volatile("" ::: "memory");

      uint4 c0 = *(const uint4*)(cand + p16 + 0);
      uint4 c1 = *(const uint4*)(cand + p16 + 4);
      uint4 c2 = *(const uint4*)(cand + p16 + 8);
      uint4 c3 = *(const uint4*)(cand + p16 + 12);
      // pairwise select on valbits; strict > keeps the LOWER wave id on ties
      // (u32 compare == f32 compare for non-negative distances)
      bool q1 = c1.x > c0.x;
      unsigned int ex = q1 ? c1.x : c0.x;
      unsigned int ey = q1 ? c1.y : c0.y;
      unsigned int ez = q1 ? c1.z : c0.z;
      unsigned int ew = q1 ? c1.w : c0.w;
      bool q2 = c3.x > c2.x;
      unsigned int fx2 = q2 ? c3.x : c2.x;
      unsigned int fy2 = q2 ? c3.y : c2.y;
      unsigned int fz2 = q2 ? c3.z : c2.z;
      unsigned int fw2 = q2 ? c3.w : c2.w;
      bool q3 = fx2 > ex;
      sx = __uint_as_float(q3 ? fy2 : ey);
      sy = __uint_as_float(q3 ? fz2 : ez);
      sz = __uint_as_float(q3 ? fw2 : ew);

      if (t == 0) { SXa[m] = sx; SYa[m] = sy; SZa[m] = sz; }
      if ((m & 15) == 15) {
        // parallel flush: lanes 0..15 of wave0 each publish one center.
        // SXa[idx] written by lane0 of the SAME wave (in-order DS).
        if (t < 16) {
          int idx = (m - 15) + t;
          float ffx = SXa[idx], ffy = SYa[idx], ffz = SZa[idx];
          size_t o = ((size_t)b * MM + idx) * 3;
          __hip_atomic_store(&pos_s_ws[o + 0], ffx, __ATOMIC_RELAXED, __HIP_MEMORY_SCOPE_AGENT);
          __hip_atomic_store(&pos_s_ws[o + 1], ffy, __ATOMIC_RELAXED, __HIP_MEMORY_SCOPE_AGENT);
          __hip_atomic_store(&pos_s_ws[o + 2], ffz, __ATOMIC_RELAXED, __HIP_MEMORY_SCOPE_AGENT);
        }
      } else if ((m & 15) == 0 && t == 0) {
        // hand-rolled release: wave0's flush stores (issued one iter ago)
        // complete at the coherence point before progress publishes.
        asm volatile("s_waitcnt vmcnt(0)" ::: "memory");
        __hip_atomic_store(&progress[b * PSTRIDE], (unsigned int)m,
                           __ATOMIC_RELAXED, __HIP_MEMORY_SCOPE_AGENT);
      }
    }
    __syncthreads();   // full barrier: SXa final values visible to all threads
    if (t == 0) {
      // final publish: last flush (m=1023) covered centers 1008..1023.
      asm volatile("s_waitcnt vmcnt(0)" ::: "memory");
      __hip_atomic_store(&progress[b * PSTRIDE], (unsigned int)MM,
                         __ATOMIC_RELAXED, __HIP_MEMORY_SCOPE_AGENT);
    }
    for (int i = t; i < MM; i += FTH) {
      size_t o = ((size_t)b * MM + i) * 3;
      pos_s_out[o + 0] = SXa[i];
      pos_s_out[o + 1] = SYa[i];
      pos_s_out[o + 2] = SZa[i];
    }
    return;
  }

  // ============ CONSUMER: two 4-wave pipelines (halves h=0,1) ============
  const int h = t >> 8;            // half id
  const int th = t & 255;          // half-local thread id
  const int wvh = (t >> 6) & 3;    // half-local wave id
  unsigned char* HB = LBUF + h * HSTRIDE;
  unsigned short* Ah = (unsigned short*)HB;
  unsigned short* Al = (unsigned short*)(HB + 64 * SA * 2);
  unsigned short* Hh = (unsigned short*)HB;
  unsigned short* Hl = (unsigned short*)(HB + 64 * SH * 2);
  int* nbr_s = (int*)(HB + 34816);
  unsigned long long* masksL = (unsigned long long*)(HB + 35072);
  int* prefixL = (int*)(HB + 35584);
  float* ctr = (float*)(HB + 35840);
  int* cntS = (int*)(HB + 35856);
  volatile int* cidShare = (int*)(LBUF + 83960);   // block-wide
  const int r = lane & 15, q = lane >> 4;
  const int wbase = wvh * 32;

  while (true) {
    if (t == 0) {
      unsigned int i = __hip_atomic_fetch_add(claim, 2u, __ATOMIC_RELAXED,
                                              __HIP_MEMORY_SCOPE_AGENT);
      *cidShare = (int)i;
    }
    __syncthreads();
    int i0 = *cidShare;
    if (i0 >= BB * MM) break;                      // uniform exit
    const int i = i0 + h;
    const bool active = (i < BB * MM);
    const int cid = active ? (((i & 15) << 10) | (i >> 4)) : 0;
    const int b = cid >> 10;
    const int m = cid & 1023;

    if (active && th < 64) {   // half's wave 0 polls production progress
      while ((int)__hip_atomic_load(&progress[b * PSTRIDE], __ATOMIC_RELAXED,
                                    __HIP_MEMORY_SCOPE_AGENT) <= m)
        __builtin_amdgcn_s_sleep(64);
    }
    if (active && th < 3)
      ctr[th] = __hip_atomic_load(&pos_s_ws[(size_t)cid * 3 + th],
                                  __ATOMIC_RELAXED, __HIP_MEMORY_SCOPE_AGENT);
    __syncthreads();

    // ---- ballq: 4-wave mask pass + prefix + compaction (per half) ----
    const float sx = ctr[0], sy = ctr[1], sz = ctr[2];
    const float sn = (sx * sx + sy * sy) + sz * sz;
    const float* pb = pos + (size_t)b * NN * 3;
    if (active) {
#pragma unroll
      for (int cc = 0; cc < 16; ++cc) {
        int c = (wvh << 4) + cc;
        int n = (c << 6) + lane;
        float xx = pb[n * 3 + 0], yy = pb[n * 3 + 1], zz = pb[n * 3 + 2];
        float pnn = (xx * xx + yy * yy) + zz * zz;  // == old pn[n] bitwise
        float dot = __builtin_fmaf(sz, zz, __builtin_fmaf(sy, yy, sx * xx));
        float d2 = (sn + pnn) - 2.0f * dot;
        bool pred = d2 <= 0.04f;
        unsigned long long mask = __ballot(pred);
        if (lane == 0) masksL[c] = mask;
      }
    }
    __syncthreads();
    if (active && th < 64) {
      int pc = (int)__popcll(masksL[lane]);
      int incl = pc;
#pragma unroll
      for (int off = 1; off < 64; off <<= 1) {
        int o2 = __shfl_up(incl, off, 64);
        if (lane >= off) incl += o2;
      }
      prefixL[lane] = incl - pc;
      if (lane == 63) *cntS = incl < KK ? incl : KK;
    }
    __syncthreads();
    const int cnt = *cntS;
    if (active) {
#pragma unroll
      for (int cc = 0; cc < 16; ++cc) {
        int c = (wvh << 4) + cc;
        unsigned long long mk = masksL[c];
        bool pred = (mk >> lane) & 1ull;
        int slot = prefixL[c] + (int)__popcll(mk & ((1ull << lane) - 1ull));
        if (pred && slot < KK) nbr_s[slot] = (c << 6) + lane;
      }
    }
    __syncthreads();

    // ---- gather + hi/lo split into LDS feat planes ----
    if (active) {
      const int kn = th >> 2, p = th & 3;
      float vals[16];
      float d0 = 0.0f, d1 = 0.0f, d2v = 0.0f;
      if (kn < cnt) {
        int n = nbr_s[kn];
        const float* xp = x + ((size_t)b * NN + n) * CC + p * 16;
#pragma unroll
        for (int ii = 0; ii < 4; ++ii) {
          float4 v = ((const float4*)xp)[ii];
          vals[ii * 4 + 0] = v.x; vals[ii * 4 + 1] = v.y;
          vals[ii * 4 + 2] = v.z; vals[ii * 4 + 3] = v.w;
        }
        if (p == 0) {
          const float* pp = pos + ((size_t)b * NN + n) * 3;
          d0 = pp[0] - sx; d1 = pp[1] - sy; d2v = pp[2] - sz;
        }
      } else {
#pragma unroll
        for (int ii = 0; ii < 16; ++ii) vals[ii] = 0.0f;
      }
#pragma unroll
      for (int j = 0; j < 16; j += 2) {
        unsigned int h0, l0, h1, l1;
        split2(vals[j], h0, l0);
        split2(vals[j + 1], h1, l1);
        int c = p * 16 + j;
        *(unsigned int*)&Ah[kn * SA + c] = h0 | (h1 << 16);
        *(unsigned int*)&Al[kn * SA + c] = l0 | (l1 << 16);
      }
      if (p == 0) {
        unsigned int h0, l0, h1, l1, h2, l2;
        split2(d0, h0, l0); split2(d1, h1, l1); split2(d2v, h2, l2);
        *(unsigned int*)&Ah[kn * SA + 64] = h0 | (h1 << 16);
        *(unsigned int*)&Al[kn * SA + 64] = l0 | (l1 << 16);
        *(unsigned int*)&Ah[kn * SA + 66] = h2;
        *(unsigned int*)&Al[kn * SA + 66] = l2;
      } else if (p == 1) {
#pragma unroll
        for (int c = 68; c < 80; c += 2) {
          *(unsigned int*)&Ah[kn * SA + c] = 0u;
          *(unsigned int*)&Al[kn * SA + c] = 0u;
        }
      } else if (p == 2) {
#pragma unroll
        for (int c = 80; c < 96; c += 2) {
          *(unsigned int*)&Ah[kn * SA + c] = 0u;
          *(unsigned int*)&Al[kn * SA + c] = 0u;
        }
      }
    }
    __syncthreads();

    f32x4 acc[4][2];
#pragma unroll
    for (int mt = 0; mt < 4; ++mt)
#pragma unroll
      for (int nt = 0; nt < 2; ++nt) acc[mt][nt] = (f32x4)0.0f;

    // ---- layer 1 ----
    if (active) {
#pragma unroll
      for (int kc = 0; kc < 3; ++kc) {
        bf16x8 bh[2], bl[2];
#pragma unroll
        for (int nt = 0; nt < 2; ++nt) {
          int o = (wbase + nt * 16 + r) * KC1 + kc * 32 + q * 8;
          bh[nt] = *(const bf16x8*)(W1Th + o);
          bl[nt] = *(const bf16x8*)(W1Tl + o);
        }
#pragma unroll
        for (int mt = 0; mt < 4; ++mt) {
          int o = (mt * 16 + r) * SA + kc * 32 + q * 8;
          bf16x8 ah = *(const bf16x8*)&Ah[o];
          bf16x8 al = *(const bf16x8*)&Al[o];
#pragma unroll
          for (int nt = 0; nt < 2; ++nt) {
            acc[mt][nt] = __builtin_amdgcn_mfma_f32_16x16x32_bf16(ah, bh[nt], acc[mt][nt], 0, 0, 0);
            acc[mt][nt] = __builtin_amdgcn_mfma_f32_16x16x32_bf16(al, bh[nt], acc[mt][nt], 0, 0, 0);
            acc[mt][nt] = __builtin_amdgcn_mfma_f32_16x16x32_bf16(ah, bl[nt], acc[mt][nt], 0, 0, 0);
          }
        }
      }
    }
    __syncthreads();   // alias guard: A-plane reads done before H overwrite

    if (active) {
      float b1v[2] = { b1[wbase + r], b1[wbase + 16 + r] };
#pragma unroll
      for (int mt = 0; mt < 4; ++mt)
#pragma unroll
        for (int nt = 0; nt < 2; ++nt)
#pragma unroll
          for (int ii = 0; ii < 4; ++ii) {
            int mm = mt * 16 + q * 4 + ii;
            int n = wbase + nt * 16 + r;
            float v = fmaxf(acc[mt][nt][ii] + b1v[nt], 0.0f);
            unsigned int hh2, ll2; split2(v, hh2, ll2);
            Hh[mm * SH + n] = (unsigned short)hh2;
            Hl[mm * SH + n] = (unsigned short)ll2;
          }
    }
    __syncthreads();

    // ---- layer 2 + masked max ----
#pragma unroll
    for (int mt = 0; mt < 4; ++mt)
#pragma unroll
      for (int nt = 0; nt < 2; ++nt) acc[mt][nt] = (f32x4)0.0f;
    if (active) {
#pragma unroll
      for (int kc = 0; kc < 4; ++kc) {
        bf16x8 bh[2], bl[2];
#pragma unroll
        for (int nt = 0; nt < 2; ++nt) {
          int o = (wbase + nt * 16 + r) * HH + kc * 32 + q * 8;
          bh[nt] = *(const bf16x8*)(W2Th + o);
          bl[nt] = *(const bf16x8*)(W2Tl + o);
        }
#pragma unroll
        for (int mt = 0; mt < 4; ++mt) {
          int o = (mt * 16 + r) * SH + kc * 32 + q * 8;
          bf16x8 ah = *(const bf16x8*)&Hh[o];
          bf16x8 al = *(const bf16x8*)&Hl[o];
#pragma unroll
          for (int nt = 0; nt < 2; ++nt) {
            acc[mt][nt] = __builtin_amdgcn_mfma_f32_16x16x32_bf16(ah, bh[nt], acc[mt][nt], 0, 0, 0);
            acc[mt][nt] = __builtin_amdgcn_mfma_f32_16x16x32_bf16(al, bh[nt], acc[mt][nt], 0, 0, 0);
            acc[mt][nt] = __builtin_amdgcn_mfma_f32_16x16x32_bf16(ah, bl[nt], acc[mt][nt], 0, 0, 0);
          }
        }
      }
      float b2v[2] = { b2[wbase + r], b2[wbase + 16 + r] };
#pragma unroll
      for (int nt = 0; nt < 2; ++nt) {
        float vmax = NEGV;
#pragma unroll
        for (int mt = 0; mt < 4; ++mt)
#pragma unroll
          for (int ii = 0; ii < 4; ++ii) {
            int mm = mt * 16 + q * 4 + ii;
            float v = fmaxf(acc[mt][nt][ii] + b2v[nt], 0.0f);
            if (mm < cnt) vmax = fmaxf(vmax, v);
          }
        vmax = fmaxf(vmax, __shfl_xor(vmax, 16, 64));
        vmax = fmaxf(vmax, __shfl_xor(vmax, 32, 64));
        if (q == 0)
          out[(size_t)cid * HH + wbase + nt * 16 + r] = (cnt > 0) ? vmax : 0.0f;
      }
    }
    __syncthreads();   // LDS reuse guard before next center
  }
}

// ---------------------------------------------------------------------------
extern "C" void kernel_launch(void* const* d_in, const int* in_sizes, int n_in,
                              void* d_out, int out_size, void* d_ws, size_t ws_size,
                              hipStream_t stream) {
  const float* x   = (const float*)d_in[0];
  const float* pos = (const float*)d_in[1];
  const float* W1  = (const float*)d_in[2];
  const float* b1  = (const float*)d_in[3];
  const float* W2  = (const float*)d_in[4];
  const float* b2  = (const float*)d_in[5];
  float* out = (float*)d_out;
  float* pos_s_out = out + (size_t)BB * MM * HH;

  char* ws = (char*)d_ws;
  float* pos_s_ws = (float*)(ws);                          // 196608 B
  unsigned short* W1Th = (unsigned short*)(ws + 458752);   // 24576 B
  unsigned short* W1Tl = (unsigned short*)(ws + 483328);   // 24576 B
  unsigned short* W2Th = (unsigned short*)(ws + 507904);   // 32768 B
  unsigned short* W2Tl = (unsigned short*)(ws + 540672);   // 32768 B
  unsigned int* progress = (unsigned int*)(ws + 573440);   // 16*128 B
  unsigned int* claim    = (unsigned int*)(ws + 575488);   // 4 B

  wprep_kernel<<<HH, 128, 0, stream>>>(W1, W2, W1Th, W1Tl, W2Th, W2Tl,
                                       progress, claim);
  fused_kernel<<<GTOT, 512, 0, stream>>>(pos, x, pos_s_ws, pos_s_out,
                                         W1Th, W1Tl, W2Th, W2Tl, b1, b2, out,
                                         progress, claim);
}

// Round 10
// 753.215 us; speedup vs baseline: 1.7626x; 1.4180x over previous
//
#include <hip/hip_runtime.h>
#include <cstdint>
#include <cstddef>

#define BB 16
#define NN 4096
#define CC 64
#define MM 1024
#define KK 64
#define HH 128
#define NEGV -1.0e30f

#define FTH 256    // fps active threads (4 waves, 1/SIMD)
#define FPT 16     // points per thread (FTH*FPT == NN)
#define NPROD 16   // producer blocks (one per batch)
#define GTOT 256   // 1 block per CU
#define PSTRIDE 32 // progress counter stride in u32 (128B line per batch)

#define KC1 96     // layer-1 K dim padded (67 -> 96)
#define SA 104     // LDS stride of feat planes
#define SH 136     // LDS stride of h1 planes
#define HSTRIDE 41984  // per-half consumer LDS region

typedef __attribute__((ext_vector_type(8))) short bf16x8;
typedef __attribute__((ext_vector_type(4))) float f32x4;
typedef __attribute__((ext_vector_type(2))) float f32x2;

__device__ __forceinline__ unsigned int f2bf(float f) {
  unsigned int u = __float_as_uint(f);
  return (u + 0x7fffu + ((u >> 16) & 1u)) >> 16;
}
__device__ __forceinline__ void split2(float f, unsigned int& h, unsigned int& l) {
  h = f2bf(f);
  float hf = __uint_as_float(h << 16);
  l = f2bf(f - hf);
}

// f32 max across the wave via the proven DPP control sequence; lane 63 ends
// with the wave max (same ctrl/row-mask steps as the verified u64 chain).
template <int CTRL, int RM>
__device__ __forceinline__ float dppmaxf(float v) {
  int s = __builtin_amdgcn_update_dpp(__float_as_int(v), __float_as_int(v),
                                      CTRL, RM, 0xf, false);
  return fmaxf(v, __int_as_float(s));
}

// ---------------------------------------------------------------------------
// Weight prep + progress/claim init (block 0). pn computed inline by consumers.
// ---------------------------------------------------------------------------
__global__ __launch_bounds__(128) void wprep_kernel(
    const float* __restrict__ W1, const float* __restrict__ W2,
    unsigned short* __restrict__ W1Th, unsigned short* __restrict__ W1Tl,
    unsigned short* __restrict__ W2Th, unsigned short* __restrict__ W2Tl,
    unsigned int* __restrict__ progress, unsigned int* __restrict__ claim) {
  const int n = blockIdx.x, t = threadIdx.x;
  if (n == 0) {
    for (int j = t; j < NPROD * PSTRIDE; j += 128) progress[j] = 0u;
    if (t == 0) *claim = 0u;
  }
  if (t < KC1) {
    float v = (t < 67) ? W1[(size_t)t * HH + n] : 0.0f;
    unsigned int h, l; split2(v, h, l);
    W1Th[n * KC1 + t] = (unsigned short)h;
    W1Tl[n * KC1 + t] = (unsigned short)l;
  }
  {
    float v = W2[(size_t)t * HH + n];
    unsigned int h, l; split2(v, h, l);
    W2Th[n * HH + t] = (unsigned short)h;
    W2Tl[n * HH + t] = (unsigned short)l;
  }
}

// ---------------------------------------------------------------------------
// FUSED producer-consumer kernel, R24 == R21 RESTORED (empirical best:
// 715us fused / 749us e2e). Post-mortem ledger of deviations from R21:
//   R19 two-batch: -2x (VGPR clamp 128 -> hot-loop spill; round-cost model
//       wrong anyway). R20 2-wave: spill again (allocator ignores bounds).
//   R22 coord-carry: PromoteAlloca lowered select-tree arrays to LDS
//       (+73728B, 2x bank conflicts, -44%). R23 scalarized: LDS/conflicts
//       normalized but still +45% vs R21 — the 84-cndmask tree + 3 serial
//       variable-lane readlanes (hazard nops) on the pre-exchange critical
//       path cost more than the P4[fi] broadcast read they replaced.
// Conclusion: in this 1-wave/SIMD latency-bound loop, predicted 50-100cy
// wins are swamped by +-300cy codegen variance; R21 is the floor of this
// structure. The remaining cost is FPS's inherent serial chain (1023
// dependent steps x ~1680cy: barrier wake + one LDS round trip + DPP/ballot
// + phase A), NOT a memory/compute roofline (HBM 2%, MfmaUtil 10%).
// R21 structure: 4-wave producer, chunk mapping i=t*16+j, fused tournament
// L1, f32 DPP max + ballot/ctz + readlane(bi), raw s_barrier (lgkm-only
// drain), 2xb128 cand read, u64 ~bi tie-break, parallel flush lanes0-15,
// hand-rolled vmcnt(0) release. Selections bit-identical to reference.
// ---------------------------------------------------------------------------
__global__ __launch_bounds__(512, 2) void fused_kernel(
    const float* __restrict__ pos, const float* __restrict__ x,
    float* __restrict__ pos_s_ws, float* __restrict__ pos_s_out,
    const unsigned short* __restrict__ W1Th, const unsigned short* __restrict__ W1Tl,
    const unsigned short* __restrict__ W2Th, const unsigned short* __restrict__ W2Tl,
    const float* __restrict__ b1, const float* __restrict__ b2,
    float* __restrict__ out,
    unsigned int* __restrict__ progress, unsigned int* __restrict__ claim) {
#pragma clang fp contract(off)
  __shared__ __attribute__((aligned(16))) unsigned char LBUF[83968];
  const int t = threadIdx.x;
  const int lane = t & 63;

  if (blockIdx.x < NPROD) {
    // =================== PRODUCER: FPS for batch b ===================
    if (t >= FTH) return;            // waves 4..7 exit; barrier counts live waves
    __builtin_amdgcn_s_setprio(3);
    const int wv = t >> 6;           // 0..3
    const int b = blockIdx.x;
    float4* P4 = (float4*)LBUF;                          // 65536 B
    float* SXa = (float*)(LBUF + 65536);                 // 4096 B
    float* SYa = (float*)(LBUF + 69632);                 // 4096 B
    float* SZa = (float*)(LBUF + 73728);                 // 4096 B
    unsigned long long* cand = (unsigned long long*)(LBUF + 77824); // [2][4]
    const float* pb = pos + (size_t)b * NN * 3;

    // (a) coalesced P4 fill (interleaved mapping, for broadcast reads)
#pragma unroll
    for (int j = 0; j < FPT; ++j) {
      int i = t + j * FTH;
      P4[i] = make_float4(pb[i * 3 + 0], pb[i * 3 + 1], pb[i * 3 + 2], 0.0f);
    }
    // (b) chunk-register fill: this thread owns points t*16 .. t*16+15
    //     (lane order == global index order -> ballot tie-break is exact)
    f32x2 px[8], py[8], pz[8], dd[8];
    {
      const float4* pc4 = (const float4*)(pb + (size_t)t * 48);
      float4 f4[12];
#pragma unroll
      for (int ii = 0; ii < 12; ++ii) f4[ii] = pc4[ii];
      const float* ff = (const float*)f4;
#pragma unroll
      for (int l = 0; l < 16; ++l) {
        px[l >> 1][l & 1] = ff[l * 3 + 0];
        py[l >> 1][l & 1] = ff[l * 3 + 1];
        pz[l >> 1][l & 1] = ff[l * 3 + 2];
        dd[l >> 1][l & 1] = 3.4028234663852886e38f;
      }
    }
    __syncthreads();
    float4 c4 = P4[0];
    float sx = c4.x, sy = c4.y, sz = c4.z;
    if (t == 0) { SXa[0] = sx; SYa[0] = sy; SZa[0] = sz; }

    for (int m = 1; m < MM; ++m) {
      f32x2 s2x = {sx, sx}, s2y = {sy, sy}, s2z = {sz, sz};
      // distance update + tournament L1 fused (left-biased: first-max kept)
      float tv[8]; int ti[8];
#pragma unroll
      for (int k = 0; k < 8; ++k) {
        f32x2 dx = px[k] - s2x, dy = py[k] - s2y, dz = pz[k] - s2z;
        f32x2 d2 = (dx * dx + dy * dy) + dz * dz;   // v_pk_*, no FMA (pragma)
        float n0 = fminf(dd[k][0], d2[0]);
        float n1 = fminf(dd[k][1], d2[1]);
        dd[k][0] = n0;
        dd[k][1] = n1;
        bool c = n1 > n0;
        tv[k] = c ? n1 : n0;
        ti[k] = c ? (2 * k + 1) : (2 * k);
      }
      // tournament L2..L4
      float uv[4]; int ui[4];
#pragma unroll
      for (int k = 0; k < 4; ++k) {
        bool c = tv[2 * k + 1] > tv[2 * k];
        uv[k] = c ? tv[2 * k + 1] : tv[2 * k];
        ui[k] = c ? ti[2 * k + 1] : ti[2 * k];
      }
      float wv2[2]; int wi2[2];
#pragma unroll
      for (int k = 0; k < 2; ++k) {
        bool c = uv[2 * k + 1] > uv[2 * k];
        wv2[k] = c ? uv[2 * k + 1] : uv[2 * k];
        wi2[k] = c ? ui[2 * k + 1] : ui[2 * k];
      }
      bool cf = wv2[1] > wv2[0];
      float bv = cf ? wv2[1] : wv2[0];
      int bj = cf ? wi2[1] : wi2[0];
      int bi = t * 16 + bj;            // global point index (chunk mapping)

      // fast wave reduce: value-only DPP max -> scalar tail
      float mx = bv;
      mx = dppmaxf<0x111, 0xf>(mx);
      mx = dppmaxf<0x112, 0xf>(mx);
      mx = dppmaxf<0x114, 0xf>(mx);
      mx = dppmaxf<0x118, 0xf>(mx);
      mx = dppmaxf<0x142, 0xa>(mx);
      mx = dppmaxf<0x143, 0xc>(mx);
      float wavemax = __int_as_float(
          __builtin_amdgcn_readlane(__float_as_int(mx), 63));
      unsigned long long ball = __ballot(bv == wavemax);
      int wl = (int)__builtin_ctzll(ball);       // lowest lane == smallest idx
      int wbi = __builtin_amdgcn_readlane(bi, wl);

      const int p4 = (m & 1) * 4;
      if (lane == 63) {
        unsigned long long key =
            ((unsigned long long)__float_as_uint(wavemax) << 32) |
            (unsigned long long)(~(unsigned int)wbi);
        cand[p4 + wv] = key;
      }
      // raw barrier: drain LDS (cand write) only — no vmcnt drain here.
      asm volatile("s_waitcnt lgkmcnt(0)" ::: "memory");
      __builtin_amdgcn_s_barrier();
      asm volatile("" ::: "memory");

      ulonglong2 cA = *(const ulonglong2*)(cand + p4);
      ulonglong2 cB = *(const ulonglong2*)(cand + p4 + 2);
      unsigned long long m01 = cA.x > cA.y ? cA.x : cA.y;
      unsigned long long m23 = cB.x > cB.y ? cB.x : cB.y;
      unsigned long long best = m01 > m23 ? m01 : m23;
      int fi = (int)(~(unsigned int)(best & 0xffffffffull));
      float4 w4 = P4[fi];
      sx = w4.x; sy = w4.y; sz = w4.z;
      if (t == 0) { SXa[m] = sx; SYa[m] = sy; SZa[m] = sz; }
      if ((m & 15) == 15) {
        // parallel flush: lanes 0..15 of wave0 each publish one center.
        // SXa[idx] written by lane0 of the SAME wave (in-order DS).
        if (t < 16) {
          int idx = (m - 15) + t;
          float fx = SXa[idx], fy = SYa[idx], fz = SZa[idx];
          size_t o = ((size_t)b * MM + idx) * 3;
          __hip_atomic_store(&pos_s_ws[o + 0], fx, __ATOMIC_RELAXED, __HIP_MEMORY_SCOPE_AGENT);
          __hip_atomic_store(&pos_s_ws[o + 1], fy, __ATOMIC_RELAXED, __HIP_MEMORY_SCOPE_AGENT);
          __hip_atomic_store(&pos_s_ws[o + 2], fz, __ATOMIC_RELAXED, __HIP_MEMORY_SCOPE_AGENT);
        }
      } else if ((m & 15) == 0 && t == 0) {
        // hand-rolled release: wave0's flush stores (issued one iter ago)
        // complete at the coherence point before progress publishes.
        asm volatile("s_waitcnt vmcnt(0)" ::: "memory");
        __hip_atomic_store(&progress[b * PSTRIDE], (unsigned int)m,
                           __ATOMIC_RELAXED, __HIP_MEMORY_SCOPE_AGENT);
      }
    }
    __syncthreads();   // full barrier: SXa final values visible to all threads
    if (t == 0) {
      // final publish: last flush (m=1023) covered centers 1008..1023.
      asm volatile("s_waitcnt vmcnt(0)" ::: "memory");
      __hip_atomic_store(&progress[b * PSTRIDE], (unsigned int)MM,
                         __ATOMIC_RELAXED, __HIP_MEMORY_SCOPE_AGENT);
    }
    for (int i = t; i < MM; i += FTH) {
      size_t o = ((size_t)b * MM + i) * 3;
      pos_s_out[o + 0] = SXa[i];
      pos_s_out[o + 1] = SYa[i];
      pos_s_out[o + 2] = SZa[i];
    }
    return;
  }

  // ============ CONSUMER: two 4-wave pipelines (halves h=0,1) ============
  const int h = t >> 8;            // half id
  const int th = t & 255;          // half-local thread id
  const int wvh = (t >> 6) & 3;    // half-local wave id
  unsigned char* HB = LBUF + h * HSTRIDE;
  unsigned short* Ah = (unsigned short*)HB;
  unsigned short* Al = (unsigned short*)(HB + 64 * SA * 2);
  unsigned short* Hh = (unsigned short*)HB;
  unsigned short* Hl = (unsigned short*)(HB + 64 * SH * 2);
  int* nbr_s = (int*)(HB + 34816);
  unsigned long long* masksL = (unsigned long long*)(HB + 35072);
  int* prefixL = (int*)(HB + 35584);
  float* ctr = (float*)(HB + 35840);
  int* cntS = (int*)(HB + 35856);
  volatile int* cidShare = (int*)(LBUF + 83960);   // block-wide
  const int r = lane & 15, q = lane >> 4;
  const int wbase = wvh * 32;

  while (true) {
    if (t == 0) {
      unsigned int i = __hip_atomic_fetch_add(claim, 2u, __ATOMIC_RELAXED,
                                              __HIP_MEMORY_SCOPE_AGENT);
      *cidShare = (int)i;
    }
    __syncthreads();
    int i0 = *cidShare;
    if (i0 >= BB * MM) break;                      // uniform exit
    const int i = i0 + h;
    const bool active = (i < BB * MM);
    const int cid = active ? (((i & 15) << 10) | (i >> 4)) : 0;
    const int b = cid >> 10;
    const int m = cid & 1023;

    if (active && th < 64) {   // half's wave 0 polls production progress
      while ((int)__hip_atomic_load(&progress[b * PSTRIDE], __ATOMIC_RELAXED,
                                    __HIP_MEMORY_SCOPE_AGENT) <= m)
        __builtin_amdgcn_s_sleep(64);
    }
    if (active && th < 3)
      ctr[th] = __hip_atomic_load(&pos_s_ws[(size_t)cid * 3 + th],
                                  __ATOMIC_RELAXED, __HIP_MEMORY_SCOPE_AGENT);
    __syncthreads();

    // ---- ballq: 4-wave mask pass + prefix + compaction (per half) ----
    const float sx = ctr[0], sy = ctr[1], sz = ctr[2];
    const float sn = (sx * sx + sy * sy) + sz * sz;
    const float* pb = pos + (size_t)b * NN * 3;
    if (active) {
#pragma unroll
      for (int cc = 0; cc < 16; ++cc) {
        int c = (wvh << 4) + cc;
        int n = (c << 6) + lane;
        float xx = pb[n * 3 + 0], yy = pb[n * 3 + 1], zz = pb[n * 3 + 2];
        float pnn = (xx * xx + yy * yy) + zz * zz;  // == old pn[n] bitwise
        float dot = __builtin_fmaf(sz, zz, __builtin_fmaf(sy, yy, sx * xx));
        float d2 = (sn + pnn) - 2.0f * dot;
        bool pred = d2 <= 0.04f;
        unsigned long long mask = __ballot(pred);
        if (lane == 0) masksL[c] = mask;
      }
    }
    __syncthreads();
    if (active && th < 64) {
      int pc = (int)__popcll(masksL[lane]);
      int incl = pc;
#pragma unroll
      for (int off = 1; off < 64; off <<= 1) {
        int o2 = __shfl_up(incl, off, 64);
        if (lane >= off) incl += o2;
      }
      prefixL[lane] = incl - pc;
      if (lane == 63) *cntS = incl < KK ? incl : KK;
    }
    __syncthreads();
    const int cnt = *cntS;
    if (active) {
#pragma unroll
      for (int cc = 0; cc < 16; ++cc) {
        int c = (wvh << 4) + cc;
        unsigned long long mk = masksL[c];
        bool pred = (mk >> lane) & 1ull;
        int slot = prefixL[c] + (int)__popcll(mk & ((1ull << lane) - 1ull));
        if (pred && slot < KK) nbr_s[slot] = (c << 6) + lane;
      }
    }
    __syncthreads();

    // ---- gather + hi/lo split into LDS feat planes ----
    if (active) {
      const int kn = th >> 2, p = th & 3;
      float vals[16];
      float d0 = 0.0f, d1 = 0.0f, d2v = 0.0f;
      if (kn < cnt) {
        int n = nbr_s[kn];
        const float* xp = x + ((size_t)b * NN + n) * CC + p * 16;
#pragma unroll
        for (int ii = 0; ii < 4; ++ii) {
          float4 v = ((const float4*)xp)[ii];
          vals[ii * 4 + 0] = v.x; vals[ii * 4 + 1] = v.y;
          vals[ii * 4 + 2] = v.z; vals[ii * 4 + 3] = v.w;
        }
        if (p == 0) {
          const float* pp = pos + ((size_t)b * NN + n) * 3;
          d0 = pp[0] - sx; d1 = pp[1] - sy; d2v = pp[2] - sz;
        }
      } else {
#pragma unroll
        for (int ii = 0; ii < 16; ++ii) vals[ii] = 0.0f;
      }
#pragma unroll
      for (int j = 0; j < 16; j += 2) {
        unsigned int h0, l0, h1, l1;
        split2(vals[j], h0, l0);
        split2(vals[j + 1], h1, l1);
        int c = p * 16 + j;
        *(unsigned int*)&Ah[kn * SA + c] = h0 | (h1 << 16);
        *(unsigned int*)&Al[kn * SA + c] = l0 | (l1 << 16);
      }
      if (p == 0) {
        unsigned int h0, l0, h1, l1, h2, l2;
        split2(d0, h0, l0); split2(d1, h1, l1); split2(d2v, h2, l2);
        *(unsigned int*)&Ah[kn * SA + 64] = h0 | (h1 << 16);
        *(unsigned int*)&Al[kn * SA + 64] = l0 | (l1 << 16);
        *(unsigned int*)&Ah[kn * SA + 66] = h2;
        *(unsigned int*)&Al[kn * SA + 66] = l2;
      } else if (p == 1) {
#pragma unroll
        for (int c = 68; c < 80; c += 2) {
          *(unsigned int*)&Ah[kn * SA + c] = 0u;
          *(unsigned int*)&Al[kn * SA + c] = 0u;
        }
      } else if (p == 2) {
#pragma unroll
        for (int c = 80; c < 96; c += 2) {
          *(unsigned int*)&Ah[kn * SA + c] = 0u;
          *(unsigned int*)&Al[kn * SA + c] = 0u;
        }
      }
    }
    __syncthreads();

    f32x4 acc[4][2];
#pragma unroll
    for (int mt = 0; mt < 4; ++mt)
#pragma unroll
      for (int nt = 0; nt < 2; ++nt) acc[mt][nt] = (f32x4)0.0f;

    // ---- layer 1 ----
    if (active) {
#pragma unroll
      for (int kc = 0; kc < 3; ++kc) {
        bf16x8 bh[2], bl[2];
#pragma unroll
        for (int nt = 0; nt < 2; ++nt) {
          int o = (wbase + nt * 16 + r) * KC1 + kc * 32 + q * 8;
          bh[nt] = *(const bf16x8*)(W1Th + o);
          bl[nt] = *(const bf16x8*)(W1Tl + o);
        }
#pragma unroll
        for (int mt = 0; mt < 4; ++mt) {
          int o = (mt * 16 + r) * SA + kc * 32 + q * 8;
          bf16x8 ah = *(const bf16x8*)&Ah[o];
          bf16x8 al = *(const bf16x8*)&Al[o];
#pragma unroll
          for (int nt = 0; nt < 2; ++nt) {
            acc[mt][nt] = __builtin_amdgcn_mfma_f32_16x16x32_bf16(ah, bh[nt], acc[mt][nt], 0, 0, 0);
            acc[mt][nt] = __builtin_amdgcn_mfma_f32_16x16x32_bf16(al, bh[nt], acc[mt][nt], 0, 0, 0);
            acc[mt][nt] = __builtin_amdgcn_mfma_f32_16x16x32_bf16(ah, bl[nt], acc[mt][nt], 0, 0, 0);
          }
        }
      }
    }
    __syncthreads();   // alias guard: A-plane reads done before H overwrite

    if (active) {
      float b1v[2] = { b1[wbase + r], b1[wbase + 16 + r] };
#pragma unroll
      for (int mt = 0; mt < 4; ++mt)
#pragma unroll
        for (int nt = 0; nt < 2; ++nt)
#pragma unroll
          for (int ii = 0; ii < 4; ++ii) {
            int mm = mt * 16 + q * 4 + ii;
            int n = wbase + nt * 16 + r;
            float v = fmaxf(acc[mt][nt][ii] + b1v[nt], 0.0f);
            unsigned int hh2, ll2; split2(v, hh2, ll2);
            Hh[mm * SH + n] = (unsigned short)hh2;
            Hl[mm * SH + n] = (unsigned short)ll2;
          }
    }
    __syncthreads();

    // ---- layer 2 + masked max ----
#pragma unroll
    for (int mt = 0; mt < 4; ++mt)
#pragma unroll
      for (int nt = 0; nt < 2; ++nt) acc[mt][nt] = (f32x4)0.0f;
    if (active) {
#pragma unroll
      for (int kc = 0; kc < 4; ++kc) {
        bf16x8 bh[2], bl[2];
#pragma unroll
        for (int nt = 0; nt < 2; ++nt) {
          int o = (wbase + nt * 16 + r) * HH + kc * 32 + q * 8;
          bh[nt] = *(const bf16x8*)(W2Th + o);
          bl[nt] = *(const bf16x8*)(W2Tl + o);
        }
#pragma unroll
        for (int mt = 0; mt < 4; ++mt) {
          int o = (mt * 16 + r) * SH + kc * 32 + q * 8;
          bf16x8 ah = *(const bf16x8*)&Hh[o];
          bf16x8 al = *(const bf16x8*)&Hl[o];
#pragma unroll
          for (int nt = 0; nt < 2; ++nt) {
            acc[mt][nt] = __builtin_amdgcn_mfma_f32_16x16x32_bf16(ah, bh[nt], acc[mt][nt], 0, 0, 0);
            acc[mt][nt] = __builtin_amdgcn_mfma_f32_16x16x32_bf16(al, bh[nt], acc[mt][nt], 0, 0, 0);
            acc[mt][nt] = __builtin_amdgcn_mfma_f32_16x16x32_bf16(ah, bl[nt], acc[mt][nt], 0, 0, 0);
          }
        }
      }
      float b2v[2] = { b2[wbase + r], b2[wbase + 16 + r] };
#pragma unroll
      for (int nt = 0; nt < 2; ++nt) {
        float vmax = NEGV;
#pragma unroll
        for (int mt = 0; mt < 4; ++mt)
#pragma unroll
          for (int ii = 0; ii < 4; ++ii) {
            int mm = mt * 16 + q * 4 + ii;
            float v = fmaxf(acc[mt][nt][ii] + b2v[nt], 0.0f);
            if (mm < cnt) vmax = fmaxf(vmax, v);
          }
        vmax = fmaxf(vmax, __shfl_xor(vmax, 16, 64));
        vmax = fmaxf(vmax, __shfl_xor(vmax, 32, 64));
        if (q == 0)
          out[(size_t)cid * HH + wbase + nt * 16 + r] = (cnt > 0) ? vmax : 0.0f;
      }
    }
    __syncthreads();   // LDS reuse guard before next center
  }
}

// ---------------------------------------------------------------------------
extern "C" void kernel_launch(void* const* d_in, const int* in_sizes, int n_in,
                              void* d_out, int out_size, void* d_ws, size_t ws_size,
                              hipStream_t stream) {
  const float* x   = (const float*)d_in[0];
  const float* pos = (const float*)d_in[1];
  const float* W1  = (const float*)d_in[2];
  const float* b1  = (const float*)d_in[3];
  const float* W2  = (const float*)d_in[4];
  const float* b2  = (const float*)d_in[5];
  float* out = (float*)d_out;
  float* pos_s_out = out + (size_t)BB * MM * HH;

  char* ws = (char*)d_ws;
  float* pos_s_ws = (float*)(ws);                          // 196608 B
  unsigned short* W1Th = (unsigned short*)(ws + 458752);   // 24576 B
  unsigned short* W1Tl = (unsigned short*)(ws + 483328);   // 24576 B
  unsigned short* W2Th = (unsigned short*)(ws + 507904);   // 32768 B
  unsigned short* W2Tl = (unsigned short*)(ws + 540672);   // 32768 B
  unsigned int* progress = (unsigned int*)(ws + 573440);   // 16*128 B
  unsigned int* claim    = (unsigned int*)(ws + 575488);   // 4 B

  wprep_kernel<<<HH, 128, 0, stream>>>(W1, W2, W1Th, W1Tl, W2Th, W2Tl,
                                       progress, claim);
  fused_kernel<<<GTOT, 512, 0, stream>>>(pos, x, pos_s_ws, pos_s_out,
                                         W1Th, W1Tl, W2Th, W2Tl, b1, b2, out,
                                         progress, claim);
}